// Round 10
// baseline (170.297 us; speedup 1.0000x reference)
//
#include <hip/hip_runtime.h>
#include <math.h>

#define D 128
#define GB 64      // one block per graph
#define BT 512     // 8 waves
#define ZP 264     // zsb pitch in bf16 (528 B rows, 16B-aligned, 2-way banks)
#define XLP 72     // xl_h pitch in bf16 (144 B rows)

typedef __attribute__((ext_vector_type(8))) short bf16x8;
typedef __attribute__((ext_vector_type(4))) float f32x4;
typedef __attribute__((ext_vector_type(4))) unsigned u32x4;

__device__ __forceinline__ float leaky01(float v) { return v >= 0.f ? v : 0.01f * v; }
__device__ __forceinline__ unsigned short f2bf(float f) {
    unsigned u = __float_as_uint(f);
    u += 0x7FFFu + ((u >> 16) & 1u);   // RNE (no NaN inputs here)
    return (unsigned short)(u >> 16);
}
__device__ __forceinline__ float bf2f(unsigned short s) {
    return __uint_as_float(((unsigned)s) << 16);
}

// ---- LLC-coherent ops (sc0 sc1 = bypass L1/L2; no cache invalidates/flushes) ----
__device__ __forceinline__ void st_sys_u32(unsigned* p, unsigned v) {
    asm volatile("global_store_dword %0, %1, off sc0 sc1" :: "v"(p), "v"(v) : "memory");
}
__device__ __forceinline__ void st_sys_f32(float* p, float v) {
    asm volatile("global_store_dword %0, %1, off sc0 sc1" :: "v"(p), "v"(v) : "memory");
}
__device__ __forceinline__ void st_sys_u128(unsigned* p, u32x4 v) {
    asm volatile("global_store_dwordx4 %0, %1, off sc0 sc1" :: "v"(p), "v"(v) : "memory");
}
__device__ __forceinline__ unsigned ld_sys_u32(const unsigned* p) {
    unsigned v;
    asm volatile("global_load_dword %0, %1, off sc0 sc1\n\ts_waitcnt vmcnt(0)"
                 : "=v"(v) : "v"(p) : "memory");
    return v;
}
__device__ __forceinline__ float ld_sys_f32(const float* p) {
    float v;
    asm volatile("global_load_dword %0, %1, off sc0 sc1\n\ts_waitcnt vmcnt(0)"
                 : "=v"(v) : "v"(p) : "memory");
    return v;
}
__device__ __forceinline__ u32x4 ld_sys_u128(const unsigned* p) {
    u32x4 v;
    asm volatile("global_load_dwordx4 %0, %1, off sc0 sc1\n\ts_waitcnt vmcnt(0)"
                 : "=v"(v) : "v"(p) : "memory");
    return v;
}
__device__ __forceinline__ void waitst() { asm volatile("s_waitcnt vmcnt(0)" ::: "memory"); }

// ---------------- weight pre-convert + flag zero (only prelude kernel) ----------------
// Wmt[4][128n][128k]; Wat[4][128n][256k] (k<128 -> Wa rows k; k>=128 -> k+128);
// Wlt[3][384n][128k]; Wrt[3][384n][128k]. 4 elems/thread, 480 blocks x 256.
__global__ void k_wconv(const float* __restrict__ Wm, const float* __restrict__ Wa,
                        const float* __restrict__ Wl, const float* __restrict__ Wr,
                        unsigned short* __restrict__ Wmt, unsigned short* __restrict__ Wat,
                        unsigned short* __restrict__ Wlt, unsigned short* __restrict__ Wrt,
                        unsigned* __restrict__ flags) {
    int gid = blockIdx.x * blockDim.x + threadIdx.x;
    if (blockIdx.x == 0 && threadIdx.x < 64) st_sys_u32(&flags[threadIdx.x], 0u);
    if (gid < 16384) {                       // Wmt
        int o = gid * 4;
        int s = o >> 14, rem = o & 16383, n = rem >> 7, k0 = rem & 127;
        const float* src = Wm + (size_t)s * 16384;
        unsigned short* dst = Wmt + o;
#pragma unroll
        for (int j = 0; j < 4; ++j) dst[j] = f2bf(src[(size_t)(k0 + j) * 128 + n]);
    } else if (gid < 49152) {                // Wat
        int o = (gid - 16384) * 4;
        int s = o >> 15, rem = o & 32767, n = rem >> 8, k0 = rem & 255;
        int row = (k0 < 128) ? k0 : (k0 + 128);
        const float* src = Wa + (size_t)s * 49152;
        unsigned short* dst = Wat + o;
#pragma unroll
        for (int j = 0; j < 4; ++j) dst[j] = f2bf(src[(size_t)(row + j) * 128 + n]);
    } else if (gid < 86016) {                // Wlt
        int o = (gid - 49152) * 4;
        int s = o / 49152, rem = o % 49152, n = rem >> 7, k0 = rem & 127;
        const float* src = Wl + (size_t)s * 49152;
        unsigned short* dst = Wlt + o;
#pragma unroll
        for (int j = 0; j < 4; ++j) dst[j] = f2bf(src[(size_t)(k0 + j) * 384 + n]);
    } else if (gid < 122880) {               // Wrt
        int o = (gid - 86016) * 4;
        int s = o / 49152, rem = o % 49152, n = rem >> 7, k0 = rem & 127;
        const float* src = Wr + (size_t)s * 49152;
        unsigned short* dst = Wrt + o;
#pragma unroll
        for (int j = 0; j < 4; ++j) dst[j] = f2bf(src[(size_t)(k0 + j) * 384 + n]);
    }
}

// ---------------- fused per-graph kernel (no grid sync; LLC flags only) ----------------
struct Args {
    const float* x0;
    const int* e_src; const int* e_dst;
    const unsigned short *Wmt, *Wat, *Wlt, *Wrt;
    const float *Wa, *bm, *ba, *bl, *br, *att_w, *att_bias;
    unsigned short* xg0;   // [3 steps][64][128] bf16
    float* x_att;          // [3 steps][64][128] f32
    unsigned *flagX, *flagA;
    float* out;
};

__global__ __launch_bounds__(BT) void k_mega(Args p) {
    const int tid = threadIdx.x, bid = blockIdx.x, g = bid;
    const int wave = tid >> 6, lane = tid & 63;
    const int m16 = lane & 15, kg = lane >> 4;
    const int col = wave * 16 + m16;          // output column for all GEMMs

    __shared__ unsigned short zsb[64][ZP];    // [x | agg] bf16 (33792 B)
    __shared__ unsigned short hs[64][128];    // messages (16384 B)
    __shared__ unsigned mlo[64], mhi[64];     // adjacency bitmasks (dst -> src set)
    __shared__ float att_s[3][D];
    __shared__ float xgrow[D];
    __shared__ float ygmid[D];
    __shared__ float red[4][D];

    // GAT overlays (zsb dead regions during GAT phase)
    unsigned short (*xl_h)[XLP] = (unsigned short(*)[XLP])&zsb[0][0];            // [128][72]
    float* xr_h = (float*)((char*)&zsb[0][0] + 18432);                            // [8][132]
    unsigned short* alpha = (unsigned short*)((char*)&zsb[0][0] + 18432 + 4224);  // [16][72]
    unsigned short (*xg_s)[128] = (unsigned short(*)[128])&hs[0][0];              // swizzled

    // ---- adjacency bitmask build (replaces CSR; edge set identical, max is
    // order-independent -> numerics identical to the CSR gather version) ----
    if (tid < 64) { mlo[tid] = 0u; mhi[tid] = 0u; }
    __syncthreads();
    {
        int i0 = g * 1024 + tid;
        int s1 = p.e_src[i0] - g * 64,       d1 = p.e_dst[i0] - g * 64;
        int s2 = p.e_src[i0 + 512] - g * 64, d2 = p.e_dst[i0 + 512] - g * 64;
        atomicOr(s1 < 32 ? &mlo[d1] : &mhi[d1], 1u << (s1 & 31));
        atomicOr(s2 < 32 ? &mlo[d2] : &mhi[d2], 1u << (s2 & 31));
    }

    // ---- x lives in registers across all steps ----
    float xreg[16];
    {
        const float* xp = p.x0 + (size_t)g * 64 * D;
#pragma unroll
        for (int mt = 0; mt < 4; ++mt)
#pragma unroll
            for (int r = 0; r < 4; ++r) xreg[mt * 4 + r] = xp[(mt * 16 + kg * 4 + r) * D + col];
    }
    __syncthreads();

    for (int step = 0; step < 4; ++step) {
        // ---- stage x -> zsb[:,0:128) ----
#pragma unroll
        for (int mt = 0; mt < 4; ++mt)
#pragma unroll
            for (int r = 0; r < 4; ++r) zsb[mt * 16 + kg * 4 + r][col] = f2bf(xreg[mt * 4 + r]);
        if (step < 3 && tid < 384) att_s[tid >> 7][tid & 127] = p.att_w[step * 384 + tid];
        __syncthreads();

        // ---- message GEMM: h = leaky(x @ Wm + bm) ----
        {
            const unsigned short* Wb = p.Wmt + ((size_t)(step * 128 + col) * 128 + kg * 8);
            bf16x8 bB[4];
#pragma unroll
            for (int kt = 0; kt < 4; ++kt) bB[kt] = *(const bf16x8*)(Wb + kt * 32);
            float bb = p.bm[step * 128 + col];
#pragma unroll
            for (int mt = 0; mt < 4; ++mt) {
                f32x4 acc = {0.f, 0.f, 0.f, 0.f};
#pragma unroll
                for (int kt = 0; kt < 4; ++kt) {
                    bf16x8 a = *(const bf16x8*)&zsb[mt * 16 + m16][kt * 32 + kg * 8];
                    acc = __builtin_amdgcn_mfma_f32_16x16x32_bf16(a, bB[kt], acc, 0, 0, 0);
                }
#pragma unroll
                for (int r = 0; r < 4; ++r)
                    hs[mt * 16 + kg * 4 + r][col] = f2bf(leaky01(acc[r] + bb));
            }
        }
        __syncthreads();

        // ---- seg-max via bitmasks: linear pipelined LDS reads, no indirection ----
        {
            int r0 = wave * 8;
            unsigned lo[8], hi[8];
#pragma unroll
            for (int r = 0; r < 8; ++r) {
                lo[r] = (unsigned)__builtin_amdgcn_readfirstlane((int)mlo[r0 + r]);
                hi[r] = (unsigned)__builtin_amdgcn_readfirstlane((int)mhi[r0 + r]);
            }
            float m0[8], m1[8];
#pragma unroll
            for (int r = 0; r < 8; ++r) { m0[r] = -INFINITY; m1[r] = -INFINITY; }
#pragma unroll 4
            for (int s = 0; s < 32; ++s) {
                unsigned hv = *(const unsigned*)&hs[s][lane * 2];
                float v0 = bf2f((unsigned short)(hv & 0xffffu));
                float v1 = bf2f((unsigned short)(hv >> 16));
#pragma unroll
                for (int r = 0; r < 8; ++r)
                    if ((lo[r] >> s) & 1u) { m0[r] = fmaxf(m0[r], v0); m1[r] = fmaxf(m1[r], v1); }
            }
#pragma unroll 4
            for (int s = 32; s < 64; ++s) {
                unsigned hv = *(const unsigned*)&hs[s][lane * 2];
                float v0 = bf2f((unsigned short)(hv & 0xffffu));
                float v1 = bf2f((unsigned short)(hv >> 16));
#pragma unroll
                for (int r = 0; r < 8; ++r)
                    if ((hi[r] >> (s - 32)) & 1u) { m0[r] = fmaxf(m0[r], v0); m1[r] = fmaxf(m1[r], v1); }
            }
#pragma unroll
            for (int r = 0; r < 8; ++r) {
                unsigned pk = (lo[r] | hi[r])
                                  ? (((unsigned)f2bf(m1[r]) << 16) | (unsigned)f2bf(m0[r]))
                                  : 0u;
                *(unsigned*)&zsb[r0 + r][128 + lane * 2] = pk;
            }
        }

        // ---- xgrow + exact f32 ygmid = xg @ Wa[128:256,:] ----
        if (step > 0) {
            if (tid == 0) {
                const unsigned* f = p.flagA + (step - 1) * 8 + (g >> 3);
                int it = 0;
                while (ld_sys_u32(f) == 0 && it++ < (1 << 22)) __builtin_amdgcn_s_sleep(2);
            }
            __syncthreads();
            if (tid < 128) xgrow[tid] = ld_sys_f32(p.x_att + (size_t)(step - 1) * 8192 + g * 128 + tid);
            __syncthreads();
            {
                int n = tid & 127, q = tid >> 7;
                float a = 0.f;
                const float* Wmid = p.Wa + (size_t)step * 49152 + (size_t)(128 + q * 32) * 128 + n;
#pragma unroll 8
                for (int k2 = 0; k2 < 32; ++k2) a += xgrow[q * 32 + k2] * Wmid[(size_t)k2 * 128];
                red[q][n] = a;
            }
            __syncthreads();
            if (tid < 128) ygmid[tid] = red[0][tid] + red[1][tid] + red[2][tid] + red[3][tid];
        }
        __syncthreads();   // covers seg-max writes (and ygmid)

        // ---- update GEMM K=256: x' = leaky([x|agg]@Wat + ygmid + ba) + x ----
        {
            const unsigned short* Wb = p.Wat + ((size_t)(step * 128 + col) * 256 + kg * 8);
            bf16x8 bB[8];
#pragma unroll
            for (int kt = 0; kt < 8; ++kt) bB[kt] = *(const bf16x8*)(Wb + kt * 32);
            float extra = p.ba[step * 128 + col] + (step > 0 ? ygmid[col] : 0.f);
#pragma unroll
            for (int mt = 0; mt < 4; ++mt) {
                f32x4 acc = {0.f, 0.f, 0.f, 0.f};
#pragma unroll
                for (int kt = 0; kt < 8; ++kt) {
                    bf16x8 a = *(const bf16x8*)&zsb[mt * 16 + m16][kt * 32 + kg * 8];
                    acc = __builtin_amdgcn_mfma_f32_16x16x32_bf16(a, bB[kt], acc, 0, 0, 0);
                }
#pragma unroll
                for (int r = 0; r < 4; ++r) {
                    float v = leaky01(acc[r] + extra) + xreg[mt * 4 + r];
                    xreg[mt * 4 + r] = v;
                    if (step == 3) p.out[((size_t)g * 64 + mt * 16 + kg * 4 + r) * D + col] = v;
                }
            }
        }

        // ---- GAT on graph 0 (blocks 0..7, 8 dst rows each), steps 0..2 ----
        if (step < 3 && bid < 8) {
            __syncthreads();   // all update-GEMM zsb reads done before overlay writes
            unsigned short* xg0g = p.xg0 + (size_t)step * 8192;
            if (bid == 0) {
                // xg_s (swizzled) from registers, then publish linear via LLC
#pragma unroll
                for (int mt = 0; mt < 4; ++mt)
#pragma unroll
                    for (int r = 0; r < 4; ++r) {
                        int row = mt * 16 + kg * 4 + r;
                        unsigned off = (unsigned)(row * 256 + col * 2) ^ (unsigned)((row & 7) << 4);
                        *(unsigned short*)((char*)&xg_s[0][0] + off) = f2bf(xreg[mt * 4 + r]);
                    }
                __syncthreads();
                for (int j = tid; j < 1024; j += BT) {
                    unsigned boff = (unsigned)(j * 16);
                    int row = j >> 4;
                    u32x4 v = *(u32x4*)((char*)&xg_s[0][0] + (boff ^ ((row & 7) << 4)));
                    st_sys_u128((unsigned*)((char*)xg0g + boff), v);
                }
                waitst();
                __syncthreads();
                if (tid == 0) st_sys_u32(p.flagX + step, 1u);
            } else {
                if (tid == 0) {
                    int it = 0;
                    while (ld_sys_u32(p.flagX + step) == 0 && it++ < (1 << 22))
                        __builtin_amdgcn_s_sleep(2);
                }
                __syncthreads();
                for (int j = tid; j < 1024; j += BT) {
                    unsigned boff = (unsigned)(j * 16);
                    int row = j >> 4;
                    u32x4 v = ld_sys_u128((const unsigned*)((const char*)xg0g + boff));
                    *(u32x4*)((char*)&xg_s[0][0] + (boff ^ ((row & 7) << 4))) = v;
                }
                __syncthreads();
            }

            f32x4 accO = {0.f, 0.f, 0.f, 0.f};
            for (int h = 0; h < 3; ++h) {
                // xl GEMM: xl_h[c][s] = (xg0 @ Wl + bl) for head h
                {
                    const unsigned short* Wb = p.Wlt + ((size_t)(step * 384 + h * 128 + col) * 128 + kg * 8);
                    bf16x8 bB[4];
#pragma unroll
                    for (int kt = 0; kt < 4; ++kt) bB[kt] = *(const bf16x8*)(Wb + kt * 32);
                    float bb = p.bl[step * 384 + h * 128 + col];
#pragma unroll
                    for (int mt = 0; mt < 4; ++mt) {
                        f32x4 acc = {0.f, 0.f, 0.f, 0.f};
#pragma unroll
                        for (int kt = 0; kt < 4; ++kt) {
                            int row = mt * 16 + m16;
                            unsigned off = (unsigned)(row * 256 + (kt * 32 + kg * 8) * 2) ^ (unsigned)((row & 7) << 4);
                            bf16x8 a = *(const bf16x8*)((const char*)&xg_s[0][0] + off);
                            acc = __builtin_amdgcn_mfma_f32_16x16x32_bf16(a, bB[kt], acc, 0, 0, 0);
                        }
                        int s0 = mt * 16 + kg * 4;
                        unsigned pk0 = (unsigned)f2bf(acc[0] + bb) | ((unsigned)f2bf(acc[1] + bb) << 16);
                        unsigned pk1 = (unsigned)f2bf(acc[2] + bb) | ((unsigned)f2bf(acc[3] + bb) << 16);
                        *(unsigned*)&xl_h[col][s0] = pk0;
                        *(unsigned*)&xl_h[col][s0 + 2] = pk1;
                    }
                }
                // xr GEMM: this block's 8 dst rows
                {
                    const unsigned short* Wb = p.Wrt + ((size_t)(step * 384 + h * 128 + col) * 128 + kg * 8);
                    bf16x8 bB[4];
#pragma unroll
                    for (int kt = 0; kt < 4; ++kt) bB[kt] = *(const bf16x8*)(Wb + kt * 32);
                    float bb = p.br[step * 384 + h * 128 + col];
                    f32x4 acc = {0.f, 0.f, 0.f, 0.f};
#pragma unroll
                    for (int kt = 0; kt < 4; ++kt) {
                        int row = bid * 8 + (m16 & 7);
                        unsigned off = (unsigned)(row * 256 + (kt * 32 + kg * 8) * 2) ^ (unsigned)((row & 7) << 4);
                        bf16x8 a = *(const bf16x8*)((const char*)&xg_s[0][0] + off);
                        acc = __builtin_amdgcn_mfma_f32_16x16x32_bf16(a, bB[kt], acc, 0, 0, 0);
                    }
                    if (kg < 2) {
#pragma unroll
                        for (int r = 0; r < 4; ++r) xr_h[(kg * 4 + r) * 132 + col] = acc[r] + bb;
                    }
                }
                __syncthreads();
                // logits (wave = dst, lane = src), softmax over 64 src
                {
                    float lg = 0.f;
                    const float* xrp = &xr_h[wave * 132];
                    for (int k = 0; k < 128; ++k) {
                        float t = bf2f(xl_h[k][lane]) + xrp[k];
                        t = (t >= 0.f) ? t : 0.2f * t;
                        lg += att_s[h][k] * t;
                    }
                    float mx = lg;
#pragma unroll
                    for (int o = 32; o > 0; o >>= 1) mx = fmaxf(mx, __shfl_xor(mx, o));
                    float a = __expf(lg - mx), sm = a;
#pragma unroll
                    for (int o = 32; o > 0; o >>= 1) sm += __shfl_xor(sm, o);
                    alpha[wave * 72 + lane] = f2bf(a / sm);
                }
                __syncthreads();
                // accO += alpha_h @ xl_h
#pragma unroll
                for (int kt = 0; kt < 2; ++kt) {
                    bf16x8 a = *(const bf16x8*)&alpha[m16 * 72 + kt * 32 + kg * 8];
                    bf16x8 b = *(const bf16x8*)&xl_h[col][kt * 32 + kg * 8];
                    accO = __builtin_amdgcn_mfma_f32_16x16x32_bf16(a, b, accO, 0, 0, 0);
                }
                __syncthreads();
            }
            // publish x_att rows [8*bid, 8*bid+8)
            if (kg < 2) {
#pragma unroll
                for (int r = 0; r < 4; ++r) {
                    int dg = bid * 8 + kg * 4 + r;
                    float v = leaky01(accO[r] * (1.f / 3.f) + p.att_bias[step * 128 + col]);
                    st_sys_f32(p.x_att + (size_t)step * 8192 + dg * 128 + col, v);
                }
            }
            waitst();
            __syncthreads();
            if (tid == 0) st_sys_u32(p.flagA + step * 8 + bid, 1u);
        }
        __syncthreads();   // end-of-step: zsb/hs safe to overwrite
    }
}

extern "C" void kernel_launch(void* const* d_in, const int* in_sizes, int n_in,
                              void* d_out, int out_size, void* d_ws, size_t ws_size,
                              hipStream_t stream) {
    (void)n_in; (void)out_size; (void)ws_size;
    const float* x_in     = (const float*)d_in[0];
    const int*   edge_idx = (const int*)d_in[1];
    // d_in[2] batch_ind, d_in[3] edge_complete: structurally determined -> unused
    const float* Wm  = (const float*)d_in[4];
    const float* bm  = (const float*)d_in[5];
    const float* Wa  = (const float*)d_in[6];
    const float* ba  = (const float*)d_in[7];
    const float* Wl  = (const float*)d_in[8];
    const float* bl  = (const float*)d_in[9];
    const float* Wr  = (const float*)d_in[10];
    const float* br  = (const float*)d_in[11];
    const float* att_w    = (const float*)d_in[12];
    const float* att_bias = (const float*)d_in[13];
    const int E = in_sizes[1] / 2;

    char* ws = (char*)d_ws;
    size_t off = 0;
    auto alloc = [&](size_t bytes) { void* pp = ws + off; off += (bytes + 255) & ~size_t(255); return pp; };
    unsigned short* xg0 = (unsigned short*)alloc((size_t)3 * 64 * 128 * 2);
    float* x_att        = (float*)alloc((size_t)3 * 64 * 128 * 4);
    unsigned short* Wmt = (unsigned short*)alloc((size_t)4 * 128 * 128 * 2);
    unsigned short* Wat = (unsigned short*)alloc((size_t)4 * 128 * 256 * 2);
    unsigned short* Wlt = (unsigned short*)alloc((size_t)3 * 384 * 128 * 2);
    unsigned short* Wrt = (unsigned short*)alloc((size_t)3 * 384 * 128 * 2);
    unsigned* flags     = (unsigned*)alloc(64 * 4);   // [0:4) flagX, [4:36) flagA

    k_wconv<<<480, 256, 0, stream>>>(Wm, Wa, Wl, Wr, Wmt, Wat, Wlt, Wrt, flags);

    Args a;
    a.x0 = x_in;
    a.e_src = edge_idx;
    a.e_dst = edge_idx + E;
    a.Wmt = Wmt; a.Wat = Wat; a.Wlt = Wlt; a.Wrt = Wrt;
    a.Wa = Wa; a.bm = bm; a.ba = ba; a.bl = bl; a.br = br;
    a.att_w = att_w; a.att_bias = att_bias;
    a.xg0 = xg0; a.x_att = x_att;
    a.flagX = flags; a.flagA = flags + 4;
    a.out = (float*)d_out;
    void* kargs[] = { (void*)&a };
    (void)hipLaunchCooperativeKernel((void*)k_mega, dim3(GB), dim3(BT), kargs, 0, stream);
}

// Round 11
// 146.564 us; speedup vs baseline: 1.1619x; 1.1619x over previous
//
#include <hip/hip_runtime.h>
#include <math.h>

#define D 128
#define GB 64      // one block per graph
#define BT 512     // 8 waves
#define ZP 264     // zsb pitch in bf16 (528 B rows, 16B-aligned, 2-way banks)
#define XLP 72     // xl_h pitch in bf16 (144 B rows, 16B-aligned)

typedef __attribute__((ext_vector_type(8))) short bf16x8;
typedef __attribute__((ext_vector_type(4))) float f32x4;
typedef __attribute__((ext_vector_type(4))) unsigned u32x4;

__device__ __forceinline__ float leaky01(float v) { return v >= 0.f ? v : 0.01f * v; }
__device__ __forceinline__ unsigned short f2bf(float f) {
    unsigned u = __float_as_uint(f);
    u += 0x7FFFu + ((u >> 16) & 1u);   // RNE (no NaN inputs here)
    return (unsigned short)(u >> 16);
}
__device__ __forceinline__ float bf2f(unsigned short s) {
    return __uint_as_float(((unsigned)s) << 16);
}

// ---- LLC-coherent ops (sc0 sc1 = bypass L1/L2; no cache invalidates/flushes) ----
__device__ __forceinline__ void st_sys_u32(unsigned* p, unsigned v) {
    asm volatile("global_store_dword %0, %1, off sc0 sc1" :: "v"(p), "v"(v) : "memory");
}
__device__ __forceinline__ void st_sys_u128(unsigned* p, u32x4 v) {
    asm volatile("global_store_dwordx4 %0, %1, off sc0 sc1" :: "v"(p), "v"(v) : "memory");
}
__device__ __forceinline__ unsigned ld_sys_u32(const unsigned* p) {
    unsigned v;
    asm volatile("global_load_dword %0, %1, off sc0 sc1\n\ts_waitcnt vmcnt(0)"
                 : "=v"(v) : "v"(p) : "memory");
    return v;
}
__device__ __forceinline__ u32x4 ld_sys_u128(const unsigned* p) {
    u32x4 v;
    asm volatile("global_load_dwordx4 %0, %1, off sc0 sc1\n\ts_waitcnt vmcnt(0)"
                 : "=v"(v) : "v"(p) : "memory");
    return v;
}
__device__ __forceinline__ void waitst() { asm volatile("s_waitcnt vmcnt(0)" ::: "memory"); }

// ---------------- weight pre-convert + flag zero (only prelude kernel) ----------------
// Wmt[4][128n][128k]; Wat[4][128n][256k] (k<128 -> Wa rows k; k>=128 -> k+128);
// Wlt[3][384n][128k].  (Wr stays f32 original: xr is now an exact matvec.)
__global__ void k_wconv(const float* __restrict__ Wm, const float* __restrict__ Wa,
                        const float* __restrict__ Wl,
                        unsigned short* __restrict__ Wmt, unsigned short* __restrict__ Wat,
                        unsigned short* __restrict__ Wlt,
                        unsigned* __restrict__ flags) {
    int gid = blockIdx.x * blockDim.x + threadIdx.x;
    if (blockIdx.x == 0 && threadIdx.x < 8) st_sys_u32(&flags[threadIdx.x], 0u);
    if (gid < 16384) {                       // Wmt
        int o = gid * 4;
        int s = o >> 14, rem = o & 16383, n = rem >> 7, k0 = rem & 127;
        const float* src = Wm + (size_t)s * 16384;
        unsigned short* dst = Wmt + o;
#pragma unroll
        for (int j = 0; j < 4; ++j) dst[j] = f2bf(src[(size_t)(k0 + j) * 128 + n]);
    } else if (gid < 49152) {                // Wat
        int o = (gid - 16384) * 4;
        int s = o >> 15, rem = o & 32767, n = rem >> 8, k0 = rem & 255;
        int row = (k0 < 128) ? k0 : (k0 + 128);
        const float* src = Wa + (size_t)s * 49152;
        unsigned short* dst = Wat + o;
#pragma unroll
        for (int j = 0; j < 4; ++j) dst[j] = f2bf(src[(size_t)(row + j) * 128 + n]);
    } else if (gid < 86016) {                // Wlt
        int o = (gid - 49152) * 4;
        int s = o / 49152, rem = o % 49152, n = rem >> 7, k0 = rem & 127;
        const float* src = Wl + (size_t)s * 49152;
        unsigned short* dst = Wlt + o;
#pragma unroll
        for (int j = 0; j < 4; ++j) dst[j] = f2bf(src[(size_t)(k0 + j) * 384 + n]);
    }
}

// ---------------- fused per-graph kernel (one LLC hop per step: xg0+flagX) ----------------
struct Args {
    const float* x0;
    const int* e_src; const int* e_dst;
    const unsigned short *Wmt, *Wat, *Wlt;
    const float *Wa, *Wr, *bm, *ba, *bl, *br, *att_w, *att_bias;
    unsigned short* xg0;   // [3 steps][64][128] bf16 (graph0 x, post-update)
    unsigned* flagX;       // [3]
    float* out;
};

__global__ __launch_bounds__(BT) void k_mega(Args p) {
    const int tid = threadIdx.x, bid = blockIdx.x, g = bid;
    const int wave = tid >> 6, lane = tid & 63;
    const int m16 = lane & 15, kg = lane >> 4;
    const int col = wave * 16 + m16;          // output column for GEMMs

    __shared__ unsigned short zsb[64][ZP];    // [x | agg] bf16 (33792 B)
    __shared__ unsigned short hs[64][128];    // messages | xg_s swizzled (16384 B)
    __shared__ unsigned mlo[64], mhi[64];     // adjacency bitmasks
    __shared__ float att_s[3][D];
    __shared__ float xgrow[D];                // own x_att row (GAT output), persists step->step
    __shared__ float ygmid[D];                // ygmid | xr_g (phase-disjoint reuse)
    __shared__ float red[512];                // shared reduction scratch
    __shared__ float alpha_s[64];
    __shared__ float accO_s[D];

    // GAT overlay (zsb dead region during GAT phase)
    unsigned short (*xl_h)[XLP] = (unsigned short(*)[XLP])&zsb[0][0];   // [128][72]
    unsigned short (*xg_s)[128] = (unsigned short(*)[128])&hs[0][0];    // swizzled

    // ---- adjacency bitmask build (proven r10) ----
    if (tid < 64) { mlo[tid] = 0u; mhi[tid] = 0u; }
    __syncthreads();
    {
        int i0 = g * 1024 + tid;
        int s1 = p.e_src[i0] - g * 64,       d1 = p.e_dst[i0] - g * 64;
        int s2 = p.e_src[i0 + 512] - g * 64, d2 = p.e_dst[i0 + 512] - g * 64;
        atomicOr(s1 < 32 ? &mlo[d1] : &mhi[d1], 1u << (s1 & 31));
        atomicOr(s2 < 32 ? &mlo[d2] : &mhi[d2], 1u << (s2 & 31));
    }

    // ---- x lives in registers across all steps ----
    float xreg[16];
    {
        const float* xp = p.x0 + (size_t)g * 64 * D;
#pragma unroll
        for (int mt = 0; mt < 4; ++mt)
#pragma unroll
            for (int r = 0; r < 4; ++r) xreg[mt * 4 + r] = xp[(mt * 16 + kg * 4 + r) * D + col];
    }
    __syncthreads();

    for (int step = 0; step < 4; ++step) {
        // ---- stage x -> zsb[:,0:128) ----
#pragma unroll
        for (int mt = 0; mt < 4; ++mt)
#pragma unroll
            for (int r = 0; r < 4; ++r) zsb[mt * 16 + kg * 4 + r][col] = f2bf(xreg[mt * 4 + r]);
        if (step < 3 && tid < 384) att_s[tid >> 7][tid & 127] = p.att_w[step * 384 + tid];
        __syncthreads();

        // ---- message GEMM: h = leaky(x @ Wm + bm) (verbatim r10) ----
        {
            const unsigned short* Wb = p.Wmt + ((size_t)(step * 128 + col) * 128 + kg * 8);
            bf16x8 bB[4];
#pragma unroll
            for (int kt = 0; kt < 4; ++kt) bB[kt] = *(const bf16x8*)(Wb + kt * 32);
            float bb = p.bm[step * 128 + col];
#pragma unroll
            for (int mt = 0; mt < 4; ++mt) {
                f32x4 acc = {0.f, 0.f, 0.f, 0.f};
#pragma unroll
                for (int kt = 0; kt < 4; ++kt) {
                    bf16x8 a = *(const bf16x8*)&zsb[mt * 16 + m16][kt * 32 + kg * 8];
                    acc = __builtin_amdgcn_mfma_f32_16x16x32_bf16(a, bB[kt], acc, 0, 0, 0);
                }
#pragma unroll
                for (int r = 0; r < 4; ++r)
                    hs[mt * 16 + kg * 4 + r][col] = f2bf(leaky01(acc[r] + bb));
            }
        }
        __syncthreads();

        // ---- seg-max via bitmasks (verbatim r10) ----
        {
            int r0 = wave * 8;
            unsigned lo[8], hi[8];
#pragma unroll
            for (int r = 0; r < 8; ++r) {
                lo[r] = (unsigned)__builtin_amdgcn_readfirstlane((int)mlo[r0 + r]);
                hi[r] = (unsigned)__builtin_amdgcn_readfirstlane((int)mhi[r0 + r]);
            }
            float m0[8], m1[8];
#pragma unroll
            for (int r = 0; r < 8; ++r) { m0[r] = -INFINITY; m1[r] = -INFINITY; }
#pragma unroll 4
            for (int s = 0; s < 32; ++s) {
                unsigned hv = *(const unsigned*)&hs[s][lane * 2];
                float v0 = bf2f((unsigned short)(hv & 0xffffu));
                float v1 = bf2f((unsigned short)(hv >> 16));
#pragma unroll
                for (int r = 0; r < 8; ++r)
                    if ((lo[r] >> s) & 1u) { m0[r] = fmaxf(m0[r], v0); m1[r] = fmaxf(m1[r], v1); }
            }
#pragma unroll 4
            for (int s = 32; s < 64; ++s) {
                unsigned hv = *(const unsigned*)&hs[s][lane * 2];
                float v0 = bf2f((unsigned short)(hv & 0xffffu));
                float v1 = bf2f((unsigned short)(hv >> 16));
#pragma unroll
                for (int r = 0; r < 8; ++r)
                    if ((hi[r] >> (s - 32)) & 1u) { m0[r] = fmaxf(m0[r], v0); m1[r] = fmaxf(m1[r], v1); }
            }
#pragma unroll
            for (int r = 0; r < 8; ++r) {
                unsigned pk = (lo[r] | hi[r])
                                  ? (((unsigned)f2bf(m1[r]) << 16) | (unsigned)f2bf(m0[r]))
                                  : 0u;
                *(unsigned*)&zsb[r0 + r][128 + lane * 2] = pk;
            }
        }

        // ---- ygmid = xgrow @ Wa[128:256,:]  (xgrow already in LDS from GAT step-1) ----
        if (step > 0) {
            int n = tid & 127, q = tid >> 7;
            float a = 0.f;
            const float* Wmid = p.Wa + (size_t)step * 49152 + (size_t)(128 + q * 32) * 128 + n;
#pragma unroll 8
            for (int k2 = 0; k2 < 32; ++k2) a += xgrow[q * 32 + k2] * Wmid[(size_t)k2 * 128];
            red[q * 128 + n] = a;
            __syncthreads();
            if (tid < 128) ygmid[tid] = red[tid] + red[128 + tid] + red[256 + tid] + red[384 + tid];
        }
        __syncthreads();   // covers seg-max writes (and ygmid)

        // ---- update GEMM K=256 (verbatim r10) ----
        {
            const unsigned short* Wb = p.Wat + ((size_t)(step * 128 + col) * 256 + kg * 8);
            bf16x8 bB[8];
#pragma unroll
            for (int kt = 0; kt < 8; ++kt) bB[kt] = *(const bf16x8*)(Wb + kt * 32);
            float extra = p.ba[step * 128 + col] + (step > 0 ? ygmid[col] : 0.f);
#pragma unroll
            for (int mt = 0; mt < 4; ++mt) {
                f32x4 acc = {0.f, 0.f, 0.f, 0.f};
#pragma unroll
                for (int kt = 0; kt < 8; ++kt) {
                    bf16x8 a = *(const bf16x8*)&zsb[mt * 16 + m16][kt * 32 + kg * 8];
                    acc = __builtin_amdgcn_mfma_f32_16x16x32_bf16(a, bB[kt], acc, 0, 0, 0);
                }
#pragma unroll
                for (int r = 0; r < 4; ++r) {
                    float v = leaky01(acc[r] + extra) + xreg[mt * 4 + r];
                    xreg[mt * 4 + r] = v;
                    if (step == 3) p.out[((size_t)g * 64 + mt * 16 + kg * 4 + r) * D + col] = v;
                }
            }
        }

        // ---- GAT: every block computes its OWN x_att row g (steps 0..2) ----
        if (step < 3) {
            __syncthreads();   // update-GEMM zsb reads done before overlay writes
            unsigned short* xg0g = p.xg0 + (size_t)step * 8192;
            if (bid == 0) {    // publish graph0 x (verbatim r10)
#pragma unroll
                for (int mt = 0; mt < 4; ++mt)
#pragma unroll
                    for (int r = 0; r < 4; ++r) {
                        int row = mt * 16 + kg * 4 + r;
                        unsigned off = (unsigned)(row * 256 + col * 2) ^ (unsigned)((row & 7) << 4);
                        *(unsigned short*)((char*)&xg_s[0][0] + off) = f2bf(xreg[mt * 4 + r]);
                    }
                __syncthreads();
                for (int j = tid; j < 1024; j += BT) {
                    unsigned boff = (unsigned)(j * 16);
                    int row = j >> 4;
                    u32x4 v = *(u32x4*)((char*)&xg_s[0][0] + (boff ^ ((row & 7) << 4)));
                    st_sys_u128((unsigned*)((char*)xg0g + boff), v);
                }
                waitst();
                __syncthreads();
                if (tid == 0) st_sys_u32(p.flagX + step, 1u);
            } else {
                if (tid == 0) {
                    int it = 0;
                    while (ld_sys_u32(p.flagX + step) == 0 && it++ < (1 << 22))
                        __builtin_amdgcn_s_sleep(2);
                }
                __syncthreads();
                for (int j = tid; j < 1024; j += BT) {
                    unsigned boff = (unsigned)(j * 16);
                    int row = j >> 4;
                    u32x4 v = ld_sys_u128((const unsigned*)((const char*)xg0g + boff));
                    *(u32x4*)((char*)&xg_s[0][0] + (boff ^ ((row & 7) << 4))) = v;
                }
                __syncthreads();
            }

            float* xr_g = ygmid;   // ygmid dead after update GEMM -> reuse as xr row g
            for (int h = 0; h < 3; ++h) {
                // xl GEMM (verbatim r10): xl_h[c][s] bf16
                {
                    const unsigned short* Wb = p.Wlt + ((size_t)(step * 384 + h * 128 + col) * 128 + kg * 8);
                    bf16x8 bB[4];
#pragma unroll
                    for (int kt = 0; kt < 4; ++kt) bB[kt] = *(const bf16x8*)(Wb + kt * 32);
                    float bb = p.bl[step * 384 + h * 128 + col];
#pragma unroll
                    for (int mt = 0; mt < 4; ++mt) {
                        f32x4 acc = {0.f, 0.f, 0.f, 0.f};
#pragma unroll
                        for (int kt = 0; kt < 4; ++kt) {
                            int row = mt * 16 + m16;
                            unsigned off = (unsigned)(row * 256 + (kt * 32 + kg * 8) * 2) ^ (unsigned)((row & 7) << 4);
                            bf16x8 a = *(const bf16x8*)((const char*)&xg_s[0][0] + off);
                            acc = __builtin_amdgcn_mfma_f32_16x16x32_bf16(a, bB[kt], acc, 0, 0, 0);
                        }
                        int s0 = mt * 16 + kg * 4;
                        unsigned pk0 = (unsigned)f2bf(acc[0] + bb) | ((unsigned)f2bf(acc[1] + bb) << 16);
                        unsigned pk1 = (unsigned)f2bf(acc[2] + bb) | ((unsigned)f2bf(acc[3] + bb) << 16);
                        *(unsigned*)&xl_h[col][s0] = pk0;
                        *(unsigned*)&xl_h[col][s0 + 2] = pk1;
                    }
                }
                // xr row g: exact f32 matvec (ygmid pattern), xg row g from xg_s (bf16)
                {
                    int n = tid & 127, q = tid >> 7;
                    float a = 0.f;
                    const float* Wrp = p.Wr + (size_t)step * 49152 + (size_t)(q * 32) * 384 + h * 128 + n;
#pragma unroll 8
                    for (int k2 = 0; k2 < 32; ++k2) {
                        int k = q * 32 + k2;
                        unsigned b = ((unsigned)(g * 256 + k * 2)) ^ (unsigned)((g & 7) << 4);
                        float xv = bf2f(*(const unsigned short*)((const char*)&xg_s[0][0] + b));
                        a += xv * Wrp[(size_t)k2 * 384];
                    }
                    red[q * 128 + n] = a;
                }
                __syncthreads();
                if (tid < 128)
                    xr_g[tid] = red[tid] + red[128 + tid] + red[256 + tid] + red[384 + tid]
                                + p.br[step * 384 + h * 128 + tid];
                __syncthreads();
                // logits for dst g: k split across 8 waves, lane = src
                {
                    float part = 0.f;
                    int kb = wave * 16;
#pragma unroll
                    for (int kk = 0; kk < 16; ++kk) {
                        int k = kb + kk;
                        float t = bf2f(xl_h[k][lane]) + xr_g[k];
                        t = (t >= 0.f) ? t : 0.2f * t;
                        part += att_s[h][k] * t;
                    }
                    red[wave * 64 + lane] = part;
                }
                __syncthreads();
                if (wave == 0) {
                    float lg = 0.f;
#pragma unroll
                    for (int w2 = 0; w2 < 8; ++w2) lg += red[w2 * 64 + lane];
                    float mx = lg;
#pragma unroll
                    for (int o = 32; o > 0; o >>= 1) mx = fmaxf(mx, __shfl_xor(mx, o));
                    float a = __expf(lg - mx), sm = a;
#pragma unroll
                    for (int o = 32; o > 0; o >>= 1) sm += __shfl_xor(sm, o);
                    alpha_s[lane] = a / sm;
                }
                __syncthreads();
                // PV: out[c] = sum_s alpha[s]*xl[c][s], s split in 4 chunks
                {
                    int c = tid & 127, q = tid >> 7;
                    float pv = 0.f;
#pragma unroll
                    for (int s2 = 0; s2 < 16; ++s2) {
                        int s = q * 16 + s2;
                        pv += alpha_s[s] * bf2f(xl_h[c][s]);
                    }
                    red[q * 128 + c] = pv;
                }
                __syncthreads();
                if (tid < 128) {
                    float s4 = red[tid] + red[128 + tid] + red[256 + tid] + red[384 + tid];
                    accO_s[tid] = (h == 0) ? s4 : accO_s[tid] + s4;
                }
                __syncthreads();   // next head rewrites xl_h/red
            }
            if (tid < 128)
                xgrow[tid] = leaky01(accO_s[tid] * (1.f / 3.f) + p.att_bias[step * 128 + tid]);
        }
        __syncthreads();   // end-of-step: zsb/hs safe to overwrite; xgrow visible
    }
}

extern "C" void kernel_launch(void* const* d_in, const int* in_sizes, int n_in,
                              void* d_out, int out_size, void* d_ws, size_t ws_size,
                              hipStream_t stream) {
    (void)n_in; (void)out_size; (void)ws_size;
    const float* x_in     = (const float*)d_in[0];
    const int*   edge_idx = (const int*)d_in[1];
    // d_in[2] batch_ind, d_in[3] edge_complete: structurally determined -> unused
    const float* Wm  = (const float*)d_in[4];
    const float* bm  = (const float*)d_in[5];
    const float* Wa  = (const float*)d_in[6];
    const float* ba  = (const float*)d_in[7];
    const float* Wl  = (const float*)d_in[8];
    const float* bl  = (const float*)d_in[9];
    const float* Wr  = (const float*)d_in[10];
    const float* br  = (const float*)d_in[11];
    const float* att_w    = (const float*)d_in[12];
    const float* att_bias = (const float*)d_in[13];
    const int E = in_sizes[1] / 2;

    char* ws = (char*)d_ws;
    size_t off = 0;
    auto alloc = [&](size_t bytes) { void* pp = ws + off; off += (bytes + 255) & ~size_t(255); return pp; };
    unsigned short* xg0 = (unsigned short*)alloc((size_t)3 * 64 * 128 * 2);
    unsigned short* Wmt = (unsigned short*)alloc((size_t)4 * 128 * 128 * 2);
    unsigned short* Wat = (unsigned short*)alloc((size_t)4 * 128 * 256 * 2);
    unsigned short* Wlt = (unsigned short*)alloc((size_t)3 * 384 * 128 * 2);
    unsigned* flags     = (unsigned*)alloc(8 * 4);

    k_wconv<<<336, 256, 0, stream>>>(Wm, Wa, Wl, Wmt, Wat, Wlt, flags);

    Args a;
    a.x0 = x_in;
    a.e_src = edge_idx;
    a.e_dst = edge_idx + E;
    a.Wmt = Wmt; a.Wat = Wat; a.Wlt = Wlt;
    a.Wa = Wa; a.Wr = Wr; a.bm = bm; a.ba = ba; a.bl = bl; a.br = br;
    a.att_w = att_w; a.att_bias = att_bias;
    a.xg0 = xg0; a.flagX = flags;
    a.out = (float*)d_out;
    void* kargs[] = { (void*)&a };
    (void)hipLaunchCooperativeKernel((void*)k_mega, dim3(GB), dim3(BT), kargs, 0, stream);
}